// Round 1
// baseline (332.764 us; speedup 1.0000x reference)
//
#include <hip/hip_runtime.h>
#include <stdint.h>

// Problem shape (fixed by setup_inputs)
#define BB 64
#define CC 128
#define HW 3136
#define NPR (CC * HW)        // 401408 elements per batch row
#define NBINS 8192
#define BIN_SHIFT 19         // key >> 19 -> top 13 bits (sign + 8 exp + 4 mantissa)

// Workspace layout (bytes):
//   [0, 512)        : bf[128] floats
//   [512, 1536)     : rowmeta int2[64]  {binstar, E}
//   [2048, 2304)    : counters u32[64]
//   [4096, 4096+2MB): hist u32[64][8192]
//   [CAND_OFF, ...) : candidates u64[64][cap]
#define ROWMETA_OFF 512
#define COUNTER_OFF 2048
#define HIST_OFF 4096
#define CAND_OFF (HIST_OFF + (size_t)BB * NBINS * 4)   // 2,101,248

__device__ __forceinline__ uint32_t tokey(float b) {
    uint32_t u = __float_as_uint(b);
    // order-preserving map: positives -> set sign bit, negatives -> flip all
    return u ^ (uint32_t)(((int32_t)u >> 31) | 0x80000000);
}

// ---------------- kernel 0: boost factors ----------------
__global__ void k_bf(const float* __restrict__ dc, const int* __restrict__ kptr,
                     float* __restrict__ bf) {
    int c = threadIdx.x;
    if (c < CC) {
        float td = (float)((double)(*kptr) / (double)NPR);  // jnp.float32(k/n)
        float d = td - dc[c];                               // fp32 subtract
        bf[c] = (float)exp((double)d);                      // best match for np fp32 exp
    }
}

// ---------------- kernel 1: per-row histogram of key top bits ----------------
__global__ __launch_bounds__(256) void k_hist(const float* __restrict__ x,
                                              const float* __restrict__ bf,
                                              uint32_t* __restrict__ hist) {
    __shared__ uint32_t lh[NBINS];                 // 32 KiB
    for (int i = threadIdx.x; i < NBINS; i += 256) lh[i] = 0;
    __syncthreads();

    int row = blockIdx.x >> 4;                     // 16 blocks per row
    int sub = blockIdx.x & 15;
    const int elems = NPR / 16;                    // 25088, multiple of HW? 25088 = 8*3136 -> channel-aligned
    int base_j = sub * elems;
    const float4* xp = (const float4*)(x + (size_t)row * NPR + base_j);
    const int nf4 = elems / 4;

    for (int t = threadIdx.x; t < nf4; t += 256) {
        float4 v = xp[t];
        int j = base_j + 4 * t;
        int c = j / HW;                            // all 4 elems same channel (HW % 4 == 0)
        float f = bf[c];
        atomicAdd(&lh[tokey(v.x * f) >> BIN_SHIFT], 1u);
        atomicAdd(&lh[tokey(v.y * f) >> BIN_SHIFT], 1u);
        atomicAdd(&lh[tokey(v.z * f) >> BIN_SHIFT], 1u);
        atomicAdd(&lh[tokey(v.w * f) >> BIN_SHIFT], 1u);
    }
    __syncthreads();
    uint32_t* gh = hist + (size_t)row * NBINS;
    for (int i = threadIdx.x; i < NBINS; i += 256) {
        uint32_t v = lh[i];
        if (v) atomicAdd(&gh[i], v);               // sparse flush: ~200 hot bins
    }
}

// ---------------- kernel 2: find boundary bin per row ----------------
__global__ __launch_bounds__(256) void k_scan(const uint32_t* __restrict__ hist,
                                              const int* __restrict__ kptr,
                                              int2* __restrict__ rowmeta) {
    int row = blockIdx.x;
    const uint32_t* gh = hist + (size_t)row * NBINS;
    uint32_t K = (uint32_t)(*kptr);
    __shared__ uint32_t csum[256];
    int t = threadIdx.x;
    int hi = NBINS - 1 - 32 * t;                   // chunk t covers bins [hi-31, hi], descending
    uint32_t s = 0;
    for (int j = 0; j < 32; j++) s += gh[hi - j];
    csum[t] = s;
    __syncthreads();
    for (int off = 1; off < 256; off <<= 1) {      // inclusive scan in descending-bin order
        uint32_t v = (t >= off) ? csum[t - off] : 0u;
        __syncthreads();
        csum[t] += v;
        __syncthreads();
    }
    uint32_t incl = csum[t];
    uint32_t excl = incl - s;
    if (excl < K && incl >= K) {                   // exactly one thread (S_t > 0 here)
        uint32_t cum = excl;
        for (int j = 0; j < 32; j++) {
            int b = hi - j;
            uint32_t h = gh[b];
            if (cum + h >= K) { rowmeta[row] = make_int2(b, (int)(K - cum)); break; }
            cum += h;
        }
    }
}

// ---------------- kernel 3: write clear winners/zeros, compact boundary bin ----------------
__global__ __launch_bounds__(256) void k_write(const float* __restrict__ x,
                                               const float* __restrict__ bf,
                                               const int2* __restrict__ rowmeta,
                                               float* __restrict__ out,
                                               unsigned long long* __restrict__ cand,
                                               uint32_t* __restrict__ counters,
                                               int cap) {
    int row = blockIdx.x >> 7;                     // one block per (row, channel)
    int c = blockIdx.x & 127;
    int bstar = rowmeta[row].x;
    float f = bf[c];

    __shared__ uint32_t lcnt;
    __shared__ uint32_t gbase;
    __shared__ unsigned long long lbuf[1024];
    if (threadIdx.x == 0) lcnt = 0;
    __syncthreads();

    size_t base = (size_t)row * NPR + (size_t)c * HW;
    const float4* xp = (const float4*)(x + base);
    float4* op = (float4*)(out + base);
    int jbase = c * HW;

    for (int t = threadIdx.x; t < HW / 4; t += 256) {
        float4 v = xp[t];
        float4 o;
        float* vi = (float*)&v;
        float* oi = (float*)&o;
        #pragma unroll
        for (int q = 0; q < 4; q++) {
            float xv = vi[q];
            uint32_t key = tokey(xv * f);
            int bin = (int)(key >> BIN_SHIFT);
            oi[q] = (bin > bstar) ? xv : 0.0f;
            if (bin == bstar) {
                uint32_t j = (uint32_t)(jbase + 4 * t + q);
                unsigned long long packed =
                    ((unsigned long long)key << 32) | (uint32_t)(~j);  // ~j: ties -> lowest idx wins
                uint32_t pos = atomicAdd(&lcnt, 1u);
                if (pos < 1024u) {
                    lbuf[pos] = packed;
                } else {                            // overflow fallback: direct append
                    uint32_t gp = atomicAdd(&counters[row], 1u);
                    if ((int)gp < cap) cand[(size_t)row * cap + gp] = packed;
                }
            }
        }
        op[t] = o;
    }
    __syncthreads();
    uint32_t m = lcnt < 1024u ? lcnt : 1024u;
    if (threadIdx.x == 0) gbase = atomicAdd(&counters[row], m);
    __syncthreads();
    for (uint32_t i = threadIdx.x; i < m; i += 256) {
        uint32_t pos = gbase + i;
        if ((int)pos < cap) cand[(size_t)row * cap + pos] = lbuf[i];
    }
}

// ---------------- kernel 4: exact radix-select among candidates + scatter ----------------
__global__ __launch_bounds__(256) void k_select(const float* __restrict__ x,
                                                float* __restrict__ out,
                                                const unsigned long long* __restrict__ cand,
                                                const uint32_t* __restrict__ counters,
                                                const int2* __restrict__ rowmeta,
                                                int cap) {
    int row = blockIdx.x;
    uint32_t cnt = counters[row];
    if ((int)cnt > cap) cnt = (uint32_t)cap;
    int E = rowmeta[row].y;
    const unsigned long long* cp = cand + (size_t)row * cap;

    __shared__ uint32_t hist[256];
    __shared__ unsigned long long sh_prefix;
    __shared__ int sh_rem;

    unsigned long long prefix = 0ull, mask = 0ull;
    int remaining = E;

    for (int shift = 56; shift >= 0; shift -= 8) {
        if (threadIdx.x < 256) hist[threadIdx.x] = 0;
        __syncthreads();
        for (uint32_t s = threadIdx.x; s < cnt; s += 256) {
            unsigned long long v = cp[s];
            if ((v & mask) == prefix)
                atomicAdd(&hist[(uint32_t)(v >> shift) & 255u], 1u);
        }
        __syncthreads();
        if (threadIdx.x == 0) {
            uint32_t cum = 0; int dstar = 0;
            for (int d = 255; d >= 0; d--) {
                uint32_t h = hist[d];
                if (cum + h >= (uint32_t)remaining) { dstar = d; break; }
                cum += h;
            }
            sh_prefix = prefix | ((unsigned long long)dstar << shift);
            sh_rem = remaining - (int)cum;
        }
        __syncthreads();
        prefix = sh_prefix;
        remaining = sh_rem;
        mask |= (0xFFull << shift);
        __syncthreads();
    }

    unsigned long long thr = prefix;               // exact E-th largest packed value
    const float* xr = x + (size_t)row * NPR;
    float* orow = out + (size_t)row * NPR;
    for (uint32_t s = threadIdx.x; s < cnt; s += 256) {
        unsigned long long v = cp[s];
        if (v >= thr) {
            uint32_t j = ~(uint32_t)v;
            orow[j] = xr[j];
        }
    }
}

extern "C" void kernel_launch(void* const* d_in, const int* in_sizes, int n_in,
                              void* d_out, int out_size, void* d_ws, size_t ws_size,
                              hipStream_t stream) {
    const float* x  = (const float*)d_in[0];
    const float* dc = (const float*)d_in[1];
    const int* kptr = (const int*)d_in[2];
    float* out = (float*)d_out;

    char* ws = (char*)d_ws;
    float* bf           = (float*)ws;
    int2* rowmeta       = (int2*)(ws + ROWMETA_OFF);
    uint32_t* counters  = (uint32_t*)(ws + COUNTER_OFF);
    uint32_t* hist      = (uint32_t*)(ws + HIST_OFF);
    unsigned long long* cand = (unsigned long long*)(ws + CAND_OFF);

    size_t cap_sz = (ws_size > CAND_OFF) ? (ws_size - CAND_OFF) / ((size_t)BB * 8) : 0;
    if (cap_sz > 65536) cap_sz = 65536;
    int cap = (int)cap_sz;

    hipMemsetAsync(ws, 0, CAND_OFF, stream);       // zero meta + counters + hist
    k_bf<<<1, 128, 0, stream>>>(dc, kptr, bf);
    k_hist<<<BB * 16, 256, 0, stream>>>(x, bf, hist);
    k_scan<<<BB, 256, 0, stream>>>(hist, kptr, rowmeta);
    k_write<<<BB * CC, 256, 0, stream>>>(x, bf, rowmeta, out, cand, counters, cap);
    k_select<<<BB, 256, 0, stream>>>(x, out, cand, counters, rowmeta, cap);
}

// Round 3
// 224.168 us; speedup vs baseline: 1.4844x; 1.4844x over previous
//
#include <hip/hip_runtime.h>
#include <stdint.h>

// Problem shape (fixed by setup_inputs)
#define BB 64
#define CC 128
#define HW 3136
#define NPR (CC * HW)        // 401408 elements per batch row
#define NBINS 8192
#define BIN_SHIFT 19         // key >> 19 -> top 13 bits (sign + 8 exp + 4 mantissa)
#define KEY_LOW 0x7FFFFu     // low 19 key bits (all candidates share the top 13)

typedef float vf4 __attribute__((ext_vector_type(4)));  // native vector for nontemporal

// Workspace layout (bytes):
//   [512, 1536)     : rowmeta int2[64]  {binstar, E}
//   [2048, 2304)    : counters u32[64]
//   [4096, 4096+2MB): hist u32[64][8192]
//   [CAND_OFF, ...) : candidates u64[64][cap]  (packed (key&0x7FFFF)<<32 | ~idx)
#define ROWMETA_OFF 512
#define COUNTER_OFF 2048
#define HIST_OFF 4096
#define CAND_OFF (HIST_OFF + (size_t)BB * NBINS * 4)

__device__ __forceinline__ uint32_t tokey(float b) {
    uint32_t u = __float_as_uint(b);
    return u ^ (uint32_t)(((int32_t)u >> 31) | 0x80000000);
}

__device__ __forceinline__ float boostf(const float* dc, int c, int K) {
    float td = (float)((double)K / (double)NPR);   // jnp.float32(k/n)
    float d = td - dc[c];
    return (float)exp((double)d);
}

// ---------------- kernel 1: per-row histogram (64 rows x 16 groups of 8 ch) --
__global__ __launch_bounds__(256) void k_hist(const float* __restrict__ x,
                                              const float* __restrict__ dc,
                                              const int* __restrict__ kptr,
                                              uint32_t* __restrict__ hist) {
    __shared__ uint32_t lh[NBINS];                 // 32 KiB
    __shared__ float sbf[8];
    for (int i = threadIdx.x; i < NBINS; i += 256) lh[i] = 0;
    if (threadIdx.x < 8) {
        int c0 = (blockIdx.x & 15) * 8;
        sbf[threadIdx.x] = boostf(dc, c0 + threadIdx.x, *kptr);
    }
    __syncthreads();

    int row = blockIdx.x >> 4;
    int c0 = (blockIdx.x & 15) * 8;
    const float4* xp = (const float4*)(x + (size_t)row * NPR + (size_t)c0 * HW);
    const int nf4 = 8 * HW / 4;                    // 6272 (784 f4 per channel)

    int t = threadIdx.x;
    for (; t + 256 < nf4; t += 512) {              // 2-way unrolled, independent loads
        float4 a = xp[t];
        float4 b = xp[t + 256];
        float fa = sbf[t / 784];
        float fb = sbf[(t + 256) / 784];
        atomicAdd(&lh[tokey(a.x * fa) >> BIN_SHIFT], 1u);
        atomicAdd(&lh[tokey(a.y * fa) >> BIN_SHIFT], 1u);
        atomicAdd(&lh[tokey(a.z * fa) >> BIN_SHIFT], 1u);
        atomicAdd(&lh[tokey(a.w * fa) >> BIN_SHIFT], 1u);
        atomicAdd(&lh[tokey(b.x * fb) >> BIN_SHIFT], 1u);
        atomicAdd(&lh[tokey(b.y * fb) >> BIN_SHIFT], 1u);
        atomicAdd(&lh[tokey(b.z * fb) >> BIN_SHIFT], 1u);
        atomicAdd(&lh[tokey(b.w * fb) >> BIN_SHIFT], 1u);
    }
    if (t < nf4) {
        float4 a = xp[t];
        float fa = sbf[t / 784];
        atomicAdd(&lh[tokey(a.x * fa) >> BIN_SHIFT], 1u);
        atomicAdd(&lh[tokey(a.y * fa) >> BIN_SHIFT], 1u);
        atomicAdd(&lh[tokey(a.z * fa) >> BIN_SHIFT], 1u);
        atomicAdd(&lh[tokey(a.w * fa) >> BIN_SHIFT], 1u);
    }
    __syncthreads();
    uint32_t* gh = hist + (size_t)row * NBINS;
    for (int i = threadIdx.x; i < NBINS; i += 256) {
        uint32_t v = lh[i];
        if (v) atomicAdd(&gh[i], v);               // sparse flush: ~200 hot bins
    }
}

// ---------------- kernel 2: find boundary bin per row ----------------
__global__ __launch_bounds__(256) void k_scan(const uint32_t* __restrict__ hist,
                                              const int* __restrict__ kptr,
                                              int2* __restrict__ rowmeta) {
    int row = blockIdx.x;
    const uint32_t* gh = hist + (size_t)row * NBINS;
    uint32_t K = (uint32_t)(*kptr);
    __shared__ uint32_t csum[256];
    int t = threadIdx.x;
    int hi = NBINS - 1 - 32 * t;                   // chunk t covers bins [hi-31, hi], descending
    uint32_t s = 0;
    for (int j = 0; j < 32; j++) s += gh[hi - j];
    csum[t] = s;
    __syncthreads();
    for (int off = 1; off < 256; off <<= 1) {      // inclusive scan in descending-bin order
        uint32_t v = (t >= off) ? csum[t - off] : 0u;
        __syncthreads();
        csum[t] += v;
        __syncthreads();
    }
    uint32_t incl = csum[t];
    uint32_t excl = incl - s;
    if (excl < K && incl >= K) {                   // exactly one thread
        uint32_t cum = excl;
        for (int j = 0; j < 32; j++) {
            int b = hi - j;
            uint32_t h = gh[b];
            if (cum + h >= K) { rowmeta[row] = make_int2(b, (int)(K - cum)); break; }
            cum += h;
        }
    }
}

// ---------------- kernel 3: write clear winners/zeros, compact boundary bin --
__global__ __launch_bounds__(256) void k_write(const float* __restrict__ x,
                                               const float* __restrict__ dc,
                                               const int* __restrict__ kptr,
                                               const int2* __restrict__ rowmeta,
                                               float* __restrict__ out,
                                               unsigned long long* __restrict__ cand,
                                               uint32_t* __restrict__ counters,
                                               int cap) {
    int row = blockIdx.x >> 4;                     // 64 rows x 16 groups of 8 channels
    int c0 = (blockIdx.x & 15) * 8;
    int bstar = rowmeta[row].x;

    __shared__ float sbf[8];
    __shared__ uint32_t lcnt;
    __shared__ uint32_t gbase;
    __shared__ unsigned long long lbuf[2048];      // 16 KiB
    if (threadIdx.x == 0) lcnt = 0;
    if (threadIdx.x < 8) sbf[threadIdx.x] = boostf(dc, c0 + threadIdx.x, *kptr);
    __syncthreads();

    size_t base = (size_t)row * NPR + (size_t)c0 * HW;
    const float4* xp = (const float4*)(x + base);
    vf4* op = (vf4*)(out + base);
    int jbase = c0 * HW;
    const int nf4 = 8 * HW / 4;                    // 6272

    int t = threadIdx.x;
    for (; t + 256 < nf4; t += 512) {
        float4 a = xp[t];
        float4 b = xp[t + 256];
        float fa = sbf[t / 784];
        float fb = sbf[(t + 256) / 784];
        vf4 oa, ob;
        float* ai = (float*)&a;
        float* bi = (float*)&b;
        #pragma unroll
        for (int q = 0; q < 4; q++) {
            float xv = ai[q];
            uint32_t key = tokey(xv * fa);
            int bin = (int)(key >> BIN_SHIFT);
            oa[q] = (bin > bstar) ? xv : 0.0f;
            if (bin == bstar) {
                uint32_t j = (uint32_t)(jbase + 4 * t + q);
                unsigned long long packed =
                    ((unsigned long long)(key & KEY_LOW) << 32) | (uint32_t)(~j);
                uint32_t pos = atomicAdd(&lcnt, 1u);
                if (pos < 2048u) lbuf[pos] = packed;
                else {
                    uint32_t gp = atomicAdd(&counters[row], 1u);
                    if ((int)gp < cap) cand[(size_t)row * cap + gp] = packed;
                }
            }
        }
        #pragma unroll
        for (int q = 0; q < 4; q++) {
            float xv = bi[q];
            uint32_t key = tokey(xv * fb);
            int bin = (int)(key >> BIN_SHIFT);
            ob[q] = (bin > bstar) ? xv : 0.0f;
            if (bin == bstar) {
                uint32_t j = (uint32_t)(jbase + 4 * (t + 256) + q);
                unsigned long long packed =
                    ((unsigned long long)(key & KEY_LOW) << 32) | (uint32_t)(~j);
                uint32_t pos = atomicAdd(&lcnt, 1u);
                if (pos < 2048u) lbuf[pos] = packed;
                else {
                    uint32_t gp = atomicAdd(&counters[row], 1u);
                    if ((int)gp < cap) cand[(size_t)row * cap + gp] = packed;
                }
            }
        }
        __builtin_nontemporal_store(oa, &op[t]);         // keep x resident in L3
        __builtin_nontemporal_store(ob, &op[t + 256]);
    }
    if (t < nf4) {
        float4 a = xp[t];
        float fa = sbf[t / 784];
        vf4 oa;
        float* ai = (float*)&a;
        #pragma unroll
        for (int q = 0; q < 4; q++) {
            float xv = ai[q];
            uint32_t key = tokey(xv * fa);
            int bin = (int)(key >> BIN_SHIFT);
            oa[q] = (bin > bstar) ? xv : 0.0f;
            if (bin == bstar) {
                uint32_t j = (uint32_t)(jbase + 4 * t + q);
                unsigned long long packed =
                    ((unsigned long long)(key & KEY_LOW) << 32) | (uint32_t)(~j);
                uint32_t pos = atomicAdd(&lcnt, 1u);
                if (pos < 2048u) lbuf[pos] = packed;
                else {
                    uint32_t gp = atomicAdd(&counters[row], 1u);
                    if ((int)gp < cap) cand[(size_t)row * cap + gp] = packed;
                }
            }
        }
        __builtin_nontemporal_store(oa, &op[t]);
    }
    __syncthreads();
    uint32_t m = lcnt < 2048u ? lcnt : 2048u;
    if (threadIdx.x == 0) gbase = atomicAdd(&counters[row], m);
    __syncthreads();
    for (uint32_t i = threadIdx.x; i < m; i += 256) {
        uint32_t pos = gbase + i;
        if ((int)pos < cap) cand[(size_t)row * cap + pos] = lbuf[i];
    }
}

// ---------------- kernel 4: exact radix-select among candidates + scatter ----
__global__ __launch_bounds__(1024) void k_select(const float* __restrict__ x,
                                                 float* __restrict__ out,
                                                 const unsigned long long* __restrict__ cand,
                                                 const uint32_t* __restrict__ counters,
                                                 const int2* __restrict__ rowmeta,
                                                 int cap) {
    int row = blockIdx.x;
    uint32_t cnt = counters[row];
    if ((int)cnt > cap) cnt = (uint32_t)cap;
    int E = rowmeta[row].y;
    const unsigned long long* cp = cand + (size_t)row * cap;
    int tid = threadIdx.x;

    __shared__ uint32_t hist[256];
    __shared__ uint32_t sufs[256];
    __shared__ unsigned long long buf[6144];       // 48 KiB survivor compaction
    __shared__ uint32_t scnt;
    __shared__ int sh_d, sh_done;

    unsigned long long prefix = 0ull, mask = 0ull, thr = 0ull;
    uint32_t remaining = (uint32_t)E;
    bool compacted = false;
    uint32_t csize = cnt;
    if (tid == 0) sh_done = 0;

    for (int shift = 48; shift >= 0; shift -= 8) {
        if (tid < 256) hist[tid] = 0;
        __syncthreads();
        if (!compacted) {
            for (uint32_t s = tid; s < cnt; s += 1024) {
                unsigned long long v = cp[s];
                if ((v & mask) == prefix)
                    atomicAdd(&hist[(uint32_t)(v >> shift) & 255u], 1u);
            }
        } else {
            for (uint32_t s = tid; s < csize; s += 1024)
                atomicAdd(&hist[(uint32_t)(buf[s] >> shift) & 255u], 1u);
        }
        __syncthreads();
        if (tid < 256) sufs[tid] = hist[tid];
        __syncthreads();
        for (int off = 1; off < 256; off <<= 1) {  // suffix sums (descending scan)
            uint32_t add = 0;
            if (tid < 256 && tid + off < 256) add = sufs[tid + off];
            __syncthreads();
            if (tid < 256) sufs[tid] += add;
            __syncthreads();
        }
        if (tid < 256) {
            uint32_t sd = sufs[tid];
            uint32_t sn = (tid < 255) ? sufs[tid + 1] : 0u;
            if (sd >= remaining && sn < remaining) sh_d = tid;
        }
        __syncthreads();
        int d = sh_d;
        uint32_t cumG = (d < 255) ? sufs[d + 1] : 0u;
        uint32_t binC = sufs[d] - cumG;
        unsigned long long npref = prefix | ((unsigned long long)(uint32_t)d << shift);
        bool done = (sufs[d] == remaining);        // whole bin completes exactly
        if (done) {
            thr = npref;
            if (tid == 0) sh_done = 1;
        }
        remaining -= cumG;
        __syncthreads();                           // sufs reads done; sh_done visible
        if (!sh_done && binC <= 6144u && shift > 0) {
            if (tid == 0) scnt = 0;
            unsigned long long keep[6]; int nk = 0;
            if (compacted) {
                for (uint32_t s = tid; s < csize; s += 1024) {
                    unsigned long long v = buf[s];
                    if (((uint32_t)(v >> shift) & 255u) == (uint32_t)d) {
                        if (nk < 6) keep[nk++] = v;
                    }
                }
            }
            __syncthreads();                       // scnt=0 visible; buf reads complete
            if (!compacted) {
                for (uint32_t s = tid; s < cnt; s += 1024) {
                    unsigned long long v = cp[s];
                    if ((v & mask) == prefix &&
                        ((uint32_t)(v >> shift) & 255u) == (uint32_t)d) {
                        uint32_t p = atomicAdd(&scnt, 1u);
                        buf[p] = v;
                    }
                }
            } else if (nk > 0) {
                uint32_t p = atomicAdd(&scnt, (uint32_t)nk);
                for (int i = 0; i < nk; i++) buf[p + i] = keep[i];
            }
            __syncthreads();
            csize = binC;
            compacted = true;
        }
        prefix = npref;
        mask |= (0xFFull << shift);
        if (sh_done) break;
    }
    if (!sh_done) thr = prefix;                    // fully resolved (all v distinct)

    const float* xr = x + (size_t)row * NPR;
    float* orow = out + (size_t)row * NPR;
    for (uint32_t s = tid; s < cnt; s += 1024) {
        unsigned long long v = cp[s];
        if (v >= thr) {
            uint32_t j = ~(uint32_t)v;
            orow[j] = xr[j];
        }
    }
}

extern "C" void kernel_launch(void* const* d_in, const int* in_sizes, int n_in,
                              void* d_out, int out_size, void* d_ws, size_t ws_size,
                              hipStream_t stream) {
    const float* x  = (const float*)d_in[0];
    const float* dc = (const float*)d_in[1];
    const int* kptr = (const int*)d_in[2];
    float* out = (float*)d_out;

    char* ws = (char*)d_ws;
    int2* rowmeta       = (int2*)(ws + ROWMETA_OFF);
    uint32_t* counters  = (uint32_t*)(ws + COUNTER_OFF);
    uint32_t* hist      = (uint32_t*)(ws + HIST_OFF);
    unsigned long long* cand = (unsigned long long*)(ws + CAND_OFF);

    size_t cap_sz = (ws_size > CAND_OFF) ? (ws_size - CAND_OFF) / ((size_t)BB * 8) : 0;
    if (cap_sz > 65536) cap_sz = 65536;
    int cap = (int)cap_sz;

    (void)hipMemsetAsync(ws, 0, CAND_OFF, stream); // zero meta + counters + hist
    k_hist<<<BB * 16, 256, 0, stream>>>(x, dc, kptr, hist);
    k_scan<<<BB, 256, 0, stream>>>(hist, kptr, rowmeta);
    k_write<<<BB * 16, 256, 0, stream>>>(x, dc, kptr, rowmeta, out, cand, counters, cap);
    k_select<<<BB, 1024, 0, stream>>>(x, out, cand, counters, rowmeta, cap);
}